// Round 1
// baseline (196.753 us; speedup 1.0000x reference)
//
#include <hip/hip_runtime.h>

#define L_LEN  1024
#define FDIM   16
#define PERIOD 24
#define HDIM   128
#define BATCH  1024
#define DDIM   (L_LEN*FDIM)      // 16384
#define NH3    (3*HDIM)          // 384
#define THALF  12
#define NCLS   10
#define FH     (FDIM*HDIM)       // 2048

typedef short bf16x8 __attribute__((ext_vector_type(8)));
typedef float f32x4  __attribute__((ext_vector_type(4)));

__device__ __forceinline__ unsigned short f2bf(float f) {
    unsigned int u = __float_as_uint(f);
    u += 0x7FFFu + ((u >> 16) & 1u);           // round-to-nearest-even
    return (unsigned short)(u >> 16);
}
__device__ __forceinline__ float cinv(int p) { return (p < 16) ? (1.0f/43.0f) : (1.0f/42.0f); }

// ---------------- kernel 0: fused = broadcast bias ----------------
__global__ void init_fused(const float* __restrict__ be0, const float* __restrict__ be1,
                           const float* __restrict__ be2, float* __restrict__ fused) {
    int idx = blockIdx.x * blockDim.x + threadIdx.x;
    if (idx >= BATCH * NH3) return;
    int j = idx % NH3;
    float b = (j < HDIM) ? be0[j] : (j < 2*HDIM ? be1[j - HDIM] : be2[j - 2*HDIM]);
    fused[idx] = b;
}

// ---------------- kernel 1: per-phase column sums of We1, We2 ----------------
// u[w][p][fh] = sum_{l % 24 == p} We_w[l*2048 + fh]
__global__ void phase_sums(const float* __restrict__ We1, const float* __restrict__ We2,
                           float* __restrict__ u) {
    int idx = blockIdx.x * blockDim.x + threadIdx.x;   // 2*24*2048 = 98304
    if (idx >= 2 * PERIOD * FH) return;
    int w   = idx / (PERIOD * FH);
    int rem = idx % (PERIOD * FH);
    int p   = rem / FH;
    int fh  = rem % FH;
    const float* W = (w == 0) ? We1 : We2;
    float s = 0.f;
    for (int l = p; l < L_LEN; l += PERIOD) s += W[(size_t)l * FH + fh];
    u[idx] = s;
}

// ---------------- kernel 2: build W' (bf16), layout Wp[n][k], k = l*16 + f ----------------
// block: 128 threads = (f 0..15) x (hsub 0..7); grid (16 hgroups, 64 l-chunks of 16)
__global__ void build_wp(const float* __restrict__ We0, const float* __restrict__ We2,
                         const float* __restrict__ u, unsigned short* __restrict__ Wp) {
    int f    = threadIdx.x & 15;
    int hsub = threadIdx.x >> 4;
    int h    = blockIdx.x * 8 + hsub;
    int l0   = blockIdx.y * 16;
    int fh   = f * HDIM + h;
    const float* u1 = u;
    const float* u2 = u + PERIOD * FH;

    float Sv1 = 0.f, Sv2 = 0.f;
    for (int p = 0; p < PERIOD; ++p) {
        float ci = cinv(p);
        Sv1 += u1[p * FH + fh] * ci;
        Sv2 += u2[p * FH + fh] * ci;
    }
    // sliding window sums over [l-12, l+12]
    float s0 = 0.f, s2 = 0.f;
    for (int j = l0 - THALF; j <= l0 + THALF; ++j)
        if (j >= 0 && j < L_LEN) { s0 += We0[(size_t)j * FH + fh]; s2 += We2[(size_t)j * FH + fh]; }

    const float inv25 = 1.0f / 25.0f;
    for (int l = l0; l < l0 + 16; ++l) {
        float out0 = s0 * inv25;                      // (T We0)[l]
        float mav1, mav2;
        if (l >= THALF && l < L_LEN - THALF) {        // interior: all 24 phases + repeat of (l+12)%24
            int pr = (l + THALF) % PERIOD;
            float cr = cinv(pr);
            mav1 = (Sv1 + u1[pr * FH + fh] * cr) * inv25;
            mav2 = (Sv2 + u2[pr * FH + fh] * cr) * inv25;
        } else {
            mav1 = 0.f; mav2 = 0.f;
            for (int dl = -THALF; dl <= THALF; ++dl) {
                int j = l + dl;
                if (j >= 0 && j < L_LEN) {
                    int p = j % PERIOD;
                    float ci = cinv(p);
                    mav1 += u1[p * FH + fh] * ci;
                    mav2 += u2[p * FH + fh] * ci;
                }
            }
            mav1 *= inv25; mav2 *= inv25;
        }
        int   pl  = l % PERIOD;
        float cl  = cinv(pl);
        float v1l = u1[pl * FH + fh] * cl;
        float v2l = u2[pl * FH + fh] * cl;
        float out1 = v1l - mav1;                                          // S^T We1
        float out2 = We2[(size_t)l * FH + fh] - s2 * inv25 - v2l + mav2;  // (I-T-S)^T We2

        size_t kidx = (size_t)l * FDIM + f;
        Wp[(size_t)h * DDIM + kidx]              = f2bf(out0);
        Wp[(size_t)(HDIM + h) * DDIM + kidx]     = f2bf(out1);
        Wp[(size_t)(2 * HDIM + h) * DDIM + kidx] = f2bf(out2);

        int jr = l - THALF, ja = l + THALF + 1;     // slide window to l+1
        if (jr >= 0)    { s0 -= We0[(size_t)jr * FH + fh]; s2 -= We2[(size_t)jr * FH + fh]; }
        if (ja < L_LEN) { s0 += We0[(size_t)ja * FH + fh]; s2 += We2[(size_t)ja * FH + fh]; }
    }
}

// ---------------- kernel 3: fused += x(1024x16384) @ Wp^T, bf16 MFMA, split-K ----------------
#define BM 128
#define BN 128
#define BK 32
#define SPLITK 16
#define KSPLIT (DDIM / SPLITK)   // 1024
#define KSTEPS (KSPLIT / BK)     // 32
#define LDP 40                   // padded LDS row stride (elements)

__launch_bounds__(256, 2)
__global__ void gemm_main(const float* __restrict__ x, const unsigned short* __restrict__ Wp,
                          float* __restrict__ fused) {
    __shared__ unsigned short As[BM * LDP];
    __shared__ unsigned short Bs[BN * LDP];
    int tid  = threadIdx.x;
    int m0   = blockIdx.x * BM;
    int n0   = blockIdx.y * BN;
    int k0   = blockIdx.z * KSPLIT;
    int wave = tid >> 6, lane = tid & 63;
    int wm = wave >> 1, wn = wave & 1;

    // staging: thread t covers tile row (t>>1), 16-element half (t&1)
    int ar = tid >> 1;
    int ah = (tid & 1) * 16;
    const float*          xg = x  + (size_t)(m0 + ar) * DDIM + k0 + ah;
    const unsigned short* bg = Wp + (size_t)(n0 + ar) * DDIM + k0 + ah;

    f32x4  acc[4][4] = {};
    f32x4  areg[4];
    bf16x8 breg[2];

    auto load_tile = [&](int step) {
        const float* xa = xg + step * BK;
        #pragma unroll
        for (int i = 0; i < 4; ++i) areg[i] = *(const f32x4*)(xa + i * 4);
        const unsigned short* bb = bg + step * BK;
        breg[0] = *(const bf16x8*)(bb);
        breg[1] = *(const bf16x8*)(bb + 8);
    };
    auto store_tile = [&]() {
        #pragma unroll
        for (int v = 0; v < 2; ++v) {
            bf16x8 ab;
            #pragma unroll
            for (int j = 0; j < 8; ++j) {
                int e = v * 8 + j;
                ab[j] = (short)f2bf(areg[e >> 2][e & 3]);
            }
            *(bf16x8*)&As[ar * LDP + ah + v * 8] = ab;
            *(bf16x8*)&Bs[ar * LDP + ah + v * 8] = breg[v];
        }
    };

    int frow = lane & 15;
    int kof  = (lane >> 4) * 8;

    load_tile(0);
    store_tile();
    __syncthreads();

    for (int step = 0; step < KSTEPS; ++step) {
        if (step + 1 < KSTEPS) load_tile(step + 1);   // prefetch next tile into regs
        bf16x8 af[4], bfr[4];
        #pragma unroll
        for (int i = 0; i < 4; ++i) {
            int row = wm * 64 + i * 16 + frow;
            af[i]  = *(const bf16x8*)&As[row * LDP + kof];
            int col = wn * 64 + i * 16 + frow;
            bfr[i] = *(const bf16x8*)&Bs[col * LDP + kof];
        }
        #pragma unroll
        for (int i = 0; i < 4; ++i)
            #pragma unroll
            for (int j = 0; j < 4; ++j)
                acc[i][j] = __builtin_amdgcn_mfma_f32_16x16x32_bf16(af[i], bfr[j], acc[i][j], 0, 0, 0);
        __syncthreads();
        if (step + 1 < KSTEPS) { store_tile(); __syncthreads(); }
    }

    // epilogue: C/D layout col = lane&15, row = (lane>>4)*4 + reg  [verified m89/m91]
    int orow = (lane >> 4) * 4;
    int ocol = lane & 15;
    #pragma unroll
    for (int i = 0; i < 4; ++i)
        #pragma unroll
        for (int j = 0; j < 4; ++j)
            #pragma unroll
            for (int r = 0; r < 4; ++r) {
                int b = m0 + wm * 64 + i * 16 + orow + r;
                int c = n0 + wn * 64 + j * 16 + ocol;
                atomicAdd(&fused[(size_t)b * NH3 + c], acc[i][j][r]);
            }
}

// ---------------- kernel 4a: h = relu(fused @ Wf1 + bf1) ----------------
__global__ void mlp1(const float* __restrict__ fused, const float* __restrict__ Wf1,
                     const float* __restrict__ bf1, float* __restrict__ h) {
    int b = blockIdx.x;
    int j = threadIdx.x;  // 0..127
    float acc = bf1[j];
    const float* fr = fused + (size_t)b * NH3;
    for (int i = 0; i < NH3; ++i) acc = fmaf(fr[i], Wf1[(size_t)i * HDIM + j], acc);
    h[(size_t)b * HDIM + j] = fmaxf(acc, 0.f);
}

// ---------------- kernel 4b: out = h @ Wf2 + bf2 ----------------
__global__ void mlp2(const float* __restrict__ h, const float* __restrict__ Wf2,
                     const float* __restrict__ bf2, float* __restrict__ out) {
    int idx = blockIdx.x * blockDim.x + threadIdx.x;
    if (idx >= BATCH * NCLS) return;
    int b = idx / NCLS, c = idx % NCLS;
    float acc = bf2[c];
    const float* hr = h + (size_t)b * HDIM;
    for (int i = 0; i < HDIM; ++i) acc = fmaf(hr[i], Wf2[(size_t)i * NCLS + c], acc);
    out[idx] = acc;
}

extern "C" void kernel_launch(void* const* d_in, const int* in_sizes, int n_in,
                              void* d_out, int out_size, void* d_ws, size_t ws_size,
                              hipStream_t stream) {
    const float* x   = (const float*)d_in[0];
    const float* We0 = (const float*)d_in[1];
    const float* be0 = (const float*)d_in[2];
    const float* We1 = (const float*)d_in[3];
    const float* be1 = (const float*)d_in[4];
    const float* We2 = (const float*)d_in[5];
    const float* be2 = (const float*)d_in[6];
    const float* Wf1 = (const float*)d_in[7];
    const float* bf1 = (const float*)d_in[8];
    const float* Wf2 = (const float*)d_in[9];
    const float* bf2 = (const float*)d_in[10];
    float* out = (float*)d_out;

    char* wsb = (char*)d_ws;
    size_t off = 0;
    unsigned short* Wp = (unsigned short*)(wsb + off); off += (size_t)NH3 * DDIM * sizeof(unsigned short); // 12.6 MB
    float* u     = (float*)(wsb + off); off += (size_t)2 * PERIOD * FH * sizeof(float);                    // 0.39 MB
    float* fused = (float*)(wsb + off); off += (size_t)BATCH * NH3 * sizeof(float);                        // 1.57 MB
    float* hbuf  = (float*)(wsb + off); off += (size_t)BATCH * HDIM * sizeof(float);                       // 0.52 MB

    init_fused<<<(BATCH * NH3 + 255) / 256, 256, 0, stream>>>(be0, be1, be2, fused);
    phase_sums<<<(2 * PERIOD * FH + 255) / 256, 256, 0, stream>>>(We1, We2, u);
    build_wp<<<dim3(16, 64), 128, 0, stream>>>(We0, We2, u, Wp);
    gemm_main<<<dim3(BATCH / BM, NH3 / BN, SPLITK), 256, 0, stream>>>(x, Wp, fused);
    mlp1<<<BATCH, HDIM, 0, stream>>>(fused, Wf1, bf1, hbuf);
    mlp2<<<(BATCH * NCLS + 255) / 256, 256, 0, stream>>>(hbuf, Wf2, bf2, out);
}

// Round 2
// 151.497 us; speedup vs baseline: 1.2987x; 1.2987x over previous
//
#include <hip/hip_runtime.h>

#define L_LEN  1024
#define FDIM   16
#define PERIOD 24
#define HDIM   128
#define BATCH  1024
#define DDIM   (L_LEN*FDIM)      // 16384
#define NH3    (3*HDIM)          // 384
#define THALF  12
#define NCLS   10
#define FH     (FDIM*HDIM)       // 2048
#define NLB    16                // l-block in build_wp

typedef short bf16x8  __attribute__((ext_vector_type(8)));
typedef short bf16x16 __attribute__((ext_vector_type(16)));
typedef float f32x4   __attribute__((ext_vector_type(4)));

__device__ __forceinline__ unsigned short f2bf(float f) {
    unsigned int u = __float_as_uint(f);
    u += 0x7FFFu + ((u >> 16) & 1u);           // round-to-nearest-even
    return (unsigned short)(u >> 16);
}
__device__ __forceinline__ float cinv(int p) { return (p < 16) ? (1.0f/43.0f) : (1.0f/42.0f); }

// ---------------- kernel 0: fused = broadcast bias ----------------
__global__ void init_fused(const float* __restrict__ be0, const float* __restrict__ be1,
                           const float* __restrict__ be2, float* __restrict__ fused) {
    int idx = blockIdx.x * blockDim.x + threadIdx.x;
    if (idx >= BATCH * NH3) return;
    int j = idx % NH3;
    float b = (j < HDIM) ? be0[j] : (j < 2*HDIM ? be1[j - HDIM] : be2[j - 2*HDIM]);
    fused[idx] = b;
}

// ---------------- kernel 1: per-phase column sums of We1, We2 ----------------
__global__ void phase_sums(const float* __restrict__ We1, const float* __restrict__ We2,
                           float* __restrict__ u) {
    int idx = blockIdx.x * blockDim.x + threadIdx.x;   // 2*24*2048 = 98304
    if (idx >= 2 * PERIOD * FH) return;
    int w   = idx / (PERIOD * FH);
    int rem = idx % (PERIOD * FH);
    int p   = rem / FH;
    int fh  = rem % FH;
    const float* W = (w == 0) ? We1 : We2;
    float s = 0.f;
    for (int l = p; l < L_LEN; l += PERIOD) s += W[(size_t)l * FH + fh];
    u[idx] = s;
}

// ---------------- kernel 2: build W' (bf16), layout Wp[n][k], k = l*16 + f ----------------
// grid (8 h-groups of 16, 64 l-strips of 16); block 256 = (f = tid>>4) x (h = tid&15)
// Reads h-lane-fast (64B coalesced chunks); LDS transpose; writes f-fast (32B/thread runs).
__global__ void build_wp(const float* __restrict__ We0, const float* __restrict__ We2,
                         const float* __restrict__ u, unsigned short* __restrict__ Wp) {
    __shared__ unsigned short tile[3][16][NLB][16];   // [mat][h][l][f] = 24 KB
    int f  = threadIdx.x >> 4;
    int hl = threadIdx.x & 15;
    int h  = blockIdx.x * 16 + hl;
    int l0 = blockIdx.y * NLB;
    int fh = f * HDIM + h;
    const float* u1 = u;
    const float* u2 = u + PERIOD * FH;

    float Sv1 = 0.f, Sv2 = 0.f;
    for (int p = 0; p < PERIOD; ++p) {
        float ci = cinv(p);
        Sv1 += u1[p * FH + fh] * ci;
        Sv2 += u2[p * FH + fh] * ci;
    }
    // sliding window sums over [l0-12, l0+12]
    float s0 = 0.f, s2 = 0.f;
    for (int j = l0 - THALF; j <= l0 + THALF; ++j)
        if (j >= 0 && j < L_LEN) { s0 += We0[(size_t)j * FH + fh]; s2 += We2[(size_t)j * FH + fh]; }

    const float inv25 = 1.0f / 25.0f;
    for (int l = l0; l < l0 + NLB; ++l) {
        float out0 = s0 * inv25;                      // (T We0)[l]
        float mav1, mav2;
        if (l >= THALF && l < L_LEN - THALF) {        // interior: all 24 phases + repeat of (l+12)%24
            int pr = (l + THALF) % PERIOD;
            float cr = cinv(pr);
            mav1 = (Sv1 + u1[pr * FH + fh] * cr) * inv25;
            mav2 = (Sv2 + u2[pr * FH + fh] * cr) * inv25;
        } else {
            mav1 = 0.f; mav2 = 0.f;
            for (int dl = -THALF; dl <= THALF; ++dl) {
                int j = l + dl;
                if (j >= 0 && j < L_LEN) {
                    int p = j % PERIOD;
                    float ci = cinv(p);
                    mav1 += u1[p * FH + fh] * ci;
                    mav2 += u2[p * FH + fh] * ci;
                }
            }
            mav1 *= inv25; mav2 *= inv25;
        }
        int   pl  = l % PERIOD;
        float cl  = cinv(pl);
        float v1l = u1[pl * FH + fh] * cl;
        float v2l = u2[pl * FH + fh] * cl;
        float out1 = v1l - mav1;                                          // S^T We1
        float out2 = We2[(size_t)l * FH + fh] - s2 * inv25 - v2l + mav2;  // (I-T-S)^T We2

        tile[0][hl][l - l0][f] = f2bf(out0);
        tile[1][hl][l - l0][f] = f2bf(out1);
        tile[2][hl][l - l0][f] = f2bf(out2);

        int jr = l - THALF, ja = l + THALF + 1;     // slide window to l+1
        if (jr >= 0)    { s0 -= We0[(size_t)jr * FH + fh]; s2 -= We2[(size_t)jr * FH + fh]; }
        if (ja < L_LEN) { s0 += We0[(size_t)ja * FH + fh]; s2 += We2[(size_t)ja * FH + fh]; }
    }
    __syncthreads();

    // write phase: thread -> (h2 = tid>>4, ll = tid&15); 32 contiguous bytes per mat
    int h2 = threadIdx.x >> 4, ll = threadIdx.x & 15;
    int hrow = blockIdx.x * 16 + h2;
    #pragma unroll
    for (int m = 0; m < 3; ++m) {
        bf16x16 v = *(const bf16x16*)&tile[m][h2][ll][0];
        *(bf16x16*)&Wp[(size_t)(m * HDIM + hrow) * DDIM + (size_t)(l0 + ll) * FDIM] = v;
    }
}

// ---------------- kernel 3: fused += x(1024x16384) @ Wp^T, bf16 MFMA, split-K ----------------
#define BM 128
#define BN 128
#define BK 32
#define SPLITK 16
#define KSPLIT (DDIM / SPLITK)   // 1024
#define KSTEPS (KSPLIT / BK)     // 32
#define LDP 40                   // padded LDS row stride (elements)

__launch_bounds__(256, 2)
__global__ void gemm_main(const float* __restrict__ x, const unsigned short* __restrict__ Wp,
                          float* __restrict__ fused) {
    __shared__ unsigned short As[BM * LDP];
    __shared__ unsigned short Bs[BN * LDP];
    int tid  = threadIdx.x;
    int m0   = blockIdx.x * BM;
    int n0   = blockIdx.y * BN;
    int k0   = blockIdx.z * KSPLIT;
    int wave = tid >> 6, lane = tid & 63;
    int wm = wave >> 1, wn = wave & 1;

    int ar = tid >> 1;
    int ah = (tid & 1) * 16;
    const float*          xg = x  + (size_t)(m0 + ar) * DDIM + k0 + ah;
    const unsigned short* bg = Wp + (size_t)(n0 + ar) * DDIM + k0 + ah;

    f32x4  acc[4][4] = {};
    f32x4  areg[4];
    bf16x8 breg[2];

    auto load_tile = [&](int step) {
        const float* xa = xg + step * BK;
        #pragma unroll
        for (int i = 0; i < 4; ++i) areg[i] = *(const f32x4*)(xa + i * 4);
        const unsigned short* bb = bg + step * BK;
        breg[0] = *(const bf16x8*)(bb);
        breg[1] = *(const bf16x8*)(bb + 8);
    };
    auto store_tile = [&]() {
        #pragma unroll
        for (int v = 0; v < 2; ++v) {
            bf16x8 ab;
            #pragma unroll
            for (int j = 0; j < 8; ++j) {
                int e = v * 8 + j;
                ab[j] = (short)f2bf(areg[e >> 2][e & 3]);
            }
            *(bf16x8*)&As[ar * LDP + ah + v * 8] = ab;
            *(bf16x8*)&Bs[ar * LDP + ah + v * 8] = breg[v];
        }
    };

    int frow = lane & 15;
    int kof  = (lane >> 4) * 8;

    load_tile(0);
    store_tile();
    __syncthreads();

    for (int step = 0; step < KSTEPS; ++step) {
        if (step + 1 < KSTEPS) load_tile(step + 1);   // prefetch next tile into regs
        bf16x8 af[4], bfr[4];
        #pragma unroll
        for (int i = 0; i < 4; ++i) {
            int row = wm * 64 + i * 16 + frow;
            af[i]  = *(const bf16x8*)&As[row * LDP + kof];
            int col = wn * 64 + i * 16 + frow;
            bfr[i] = *(const bf16x8*)&Bs[col * LDP + kof];
        }
        #pragma unroll
        for (int i = 0; i < 4; ++i)
            #pragma unroll
            for (int j = 0; j < 4; ++j)
                acc[i][j] = __builtin_amdgcn_mfma_f32_16x16x32_bf16(af[i], bfr[j], acc[i][j], 0, 0, 0);
        __syncthreads();
        if (step + 1 < KSTEPS) { store_tile(); __syncthreads(); }
    }

    // epilogue: C/D layout col = lane&15, row = (lane>>4)*4 + reg  [verified m89/m91]
    int orow = (lane >> 4) * 4;
    int ocol = lane & 15;
    #pragma unroll
    for (int i = 0; i < 4; ++i)
        #pragma unroll
        for (int j = 0; j < 4; ++j)
            #pragma unroll
            for (int r = 0; r < 4; ++r) {
                int b = m0 + wm * 64 + i * 16 + orow + r;
                int c = n0 + wn * 64 + j * 16 + ocol;
                atomicAdd(&fused[(size_t)b * NH3 + c], acc[i][j][r]);
            }
}

// ---------------- kernel 4a: h = relu(fused @ Wf1 + bf1) ----------------
__global__ void mlp1(const float* __restrict__ fused, const float* __restrict__ Wf1,
                     const float* __restrict__ bf1, float* __restrict__ h) {
    int b = blockIdx.x;
    int j = threadIdx.x;  // 0..127
    float acc = bf1[j];
    const float* fr = fused + (size_t)b * NH3;
    for (int i = 0; i < NH3; ++i) acc = fmaf(fr[i], Wf1[(size_t)i * HDIM + j], acc);
    h[(size_t)b * HDIM + j] = fmaxf(acc, 0.f);
}

// ---------------- kernel 4b: out = h @ Wf2 + bf2 ----------------
__global__ void mlp2(const float* __restrict__ h, const float* __restrict__ Wf2,
                     const float* __restrict__ bf2, float* __restrict__ out) {
    int idx = blockIdx.x * blockDim.x + threadIdx.x;
    if (idx >= BATCH * NCLS) return;
    int b = idx / NCLS, c = idx % NCLS;
    float acc = bf2[c];
    const float* hr = h + (size_t)b * HDIM;
    for (int i = 0; i < HDIM; ++i) acc = fmaf(hr[i], Wf2[(size_t)i * NCLS + c], acc);
    out[idx] = acc;
}

extern "C" void kernel_launch(void* const* d_in, const int* in_sizes, int n_in,
                              void* d_out, int out_size, void* d_ws, size_t ws_size,
                              hipStream_t stream) {
    const float* x   = (const float*)d_in[0];
    const float* We0 = (const float*)d_in[1];
    const float* be0 = (const float*)d_in[2];
    const float* We1 = (const float*)d_in[3];
    const float* be1 = (const float*)d_in[4];
    const float* We2 = (const float*)d_in[5];
    const float* be2 = (const float*)d_in[6];
    const float* Wf1 = (const float*)d_in[7];
    const float* bf1 = (const float*)d_in[8];
    const float* Wf2 = (const float*)d_in[9];
    const float* bf2 = (const float*)d_in[10];
    float* out = (float*)d_out;

    char* wsb = (char*)d_ws;
    size_t off = 0;
    unsigned short* Wp = (unsigned short*)(wsb + off); off += (size_t)NH3 * DDIM * sizeof(unsigned short); // 12.6 MB
    float* u     = (float*)(wsb + off); off += (size_t)2 * PERIOD * FH * sizeof(float);                    // 0.39 MB
    float* fused = (float*)(wsb + off); off += (size_t)BATCH * NH3 * sizeof(float);                        // 1.57 MB
    float* hbuf  = (float*)(wsb + off); off += (size_t)BATCH * HDIM * sizeof(float);                       // 0.52 MB

    init_fused<<<(BATCH * NH3 + 255) / 256, 256, 0, stream>>>(be0, be1, be2, fused);
    phase_sums<<<(2 * PERIOD * FH + 255) / 256, 256, 0, stream>>>(We1, We2, u);
    build_wp<<<dim3(8, 64), 256, 0, stream>>>(We0, We2, u, Wp);
    gemm_main<<<dim3(BATCH / BM, NH3 / BN, SPLITK), 256, 0, stream>>>(x, Wp, fused);
    mlp1<<<BATCH, HDIM, 0, stream>>>(fused, Wf1, bf1, hbuf);
    mlp2<<<(BATCH * NCLS + 255) / 256, 256, 0, stream>>>(hbuf, Wf2, bf2, out);
}